// Round 18
// baseline (216.063 us; speedup 1.0000x reference)
//
#include <hip/hip_runtime.h>

// Seq2seq LSTM, round 18: r17 (verified PASS, 230us rocprof) + LDS shaving.
// (1) af[3] (K-subtile s=3) read predicated on q==0: lanes q>=1 read provable
//     zeros (A units 208..255 are zero-init'd and never written) -> skip,
//     cutting that ds_read's data cycles ~4x.
// (2) wave-15 x-write hoisted to right after the barrier (latency hidden
//     under other waves' MFMA/trans instead of tail-serialized).
// Everything else byte-identical to r17: 256 blocks x 1024 thr x BR=16,
// full-M MFMA, DPP quad-transpose, 1 barrier/enc step (dbuf), cvt_pk h-store,
// unrolled x2, LDS xstage, pre-scaled weights.
//   i,f,o gates scaled by -log2e -> sigmoid = rcp(1 + exp2(g))
//   g gate scaled by +2*log2e   -> tanh    = 1 - 2*rcp(1 + exp2(g))

#define NTHREADS 1024
#define NBLOCKS  256
#define BR       16

typedef __attribute__((ext_vector_type(8))) short short8;
typedef __attribute__((ext_vector_type(4))) float f32x4;

#define FRAG_ELEMS 51200
#define BIAS_BYTE_OFF 204800
#define L2E 1.4426950408889634f

__device__ __forceinline__ unsigned short f2bf(float f) {
    unsigned int u = __float_as_uint(f);
    return (unsigned short)((u + 0x7fff + ((u >> 16) & 1)) >> 16);   // RNE
}
__device__ __forceinline__ float bf2f(unsigned short s) {
    return __uint_as_float(((unsigned int)s) << 16);
}
__device__ __forceinline__ unsigned short cvt1bf(float f) {     // 1-op HW RNE
    unsigned int pk;
    asm("v_cvt_pk_bf16_f32 %0, %1, %2" : "=v"(pk) : "v"(f), "v"(f));
    return (unsigned short)pk;
}
__device__ __forceinline__ float ex2(float x) {
    float r; asm("v_exp_f32 %0, %1" : "=v"(r) : "v"(x)); return r;
}
__device__ __forceinline__ float rcpf_(float x) { return __builtin_amdgcn_rcpf(x); }

__device__ __forceinline__ float dppx1(float x) {
    return __int_as_float(__builtin_amdgcn_mov_dpp(__float_as_int(x), 0xB1, 0xF, 0xF, true));
}
__device__ __forceinline__ float dppx2(float x) {
    return __int_as_float(__builtin_amdgcn_mov_dpp(__float_as_int(x), 0x4E, 0xF, 0xF, true));
}

// r10/r15-verified 4x4 quad transpose + LSTM cell update. Returns h, updates c.
__device__ __forceinline__ float trans_cell(f32x4 v, float& c, int wl) {
    float s0 = dppx1(v[0]), s1 = dppx1(v[1]), s2 = dppx1(v[2]), s3 = dppx1(v[3]);
    const bool o1 = (wl & 1) != 0;
    float a0 = o1 ? s1 : v[0];
    float a1 = o1 ? v[1] : s0;
    float a2 = o1 ? s3 : v[2];
    float a3 = o1 ? v[3] : s2;
    float u0 = dppx2(a0), u1 = dppx2(a1), u2 = dppx2(a2), u3 = dppx2(a3);
    const bool o2 = (wl & 2) != 0;
    float gi = o2 ? u2 : a0;
    float gf = o2 ? u3 : a1;
    float gg = o2 ? a2 : u0;
    float go = o2 ? a3 : u1;
    float si = rcpf_(1.f + ex2(gi));
    float sf = rcpf_(1.f + ex2(gf));
    float tg = fmaf(-2.f, rcpf_(1.f + ex2(gg)), 1.f);
    float so = rcpf_(1.f + ex2(go));
    c = fmaf(sf, c, si * tg);
    float tc = fmaf(-2.f, rcpf_(1.f + ex2(c * (2.f * L2E))), 1.f);
    return so * tc;
}

// frag[((t*4+s)*64 + lane)*8 + e] = scale(gate) * WT'[k][n], bf16  (r5-identical)
__global__ void prep_kernel(const float* __restrict__ Wih_e, const float* __restrict__ Whh_e,
                            const float* __restrict__ bih_e, const float* __restrict__ bhh_e,
                            const float* __restrict__ Wih_d, const float* __restrict__ Whh_d,
                            const float* __restrict__ bih_d, const float* __restrict__ bhh_d,
                            void* __restrict__ ws)
{
    unsigned short* frag = (unsigned short*)ws;
    float* bias = (float*)((char*)ws + BIAS_BYTE_OFF);
    int gid = blockIdx.x * blockDim.x + threadIdx.x;
    int gsz = gridDim.x * blockDim.x;
    for (int i = gid; i < 2 * FRAG_ELEMS; i += gsz) {
        int which = i / FRAG_ELEMS;
        int e = i - which * FRAG_ELEMS;
        int j8 = e & 7, lane = (e >> 3) & 63, s = (e >> 9) & 3, t = e >> 11;
        int k = s * 32 + (lane >> 4) * 8 + j8;
        int n = t * 16 + (lane & 15);
        int jcol = n >> 2, gate = n & 3, col = gate * 100 + jcol;
        float scale = (gate == 2) ? (2.f * L2E) : -L2E;
        const float* Whh = which ? Whh_d : Whh_e;
        const float* Wih = which ? Wih_d : Wih_e;
        float v = 0.f;
        if (k < 100)      v = Whh[col * 100 + k];
        else if (k < 104) v = Wih[col * 4 + (k - 100)];
        frag[i] = f2bf(v * scale);
    }
    for (int i = gid; i < 800; i += gsz) {
        int which = i / 400, n = i - which * 400;
        int jcol = n >> 2, gate = n & 3, col = gate * 100 + jcol;
        float scale = (gate == 2) ? (2.f * L2E) : -L2E;
        bias[i] = scale * (which ? (bih_d[col] + bhh_d[col]) : (bih_e[col] + bhh_e[col]));
    }
}

__global__ __launch_bounds__(NTHREADS, 4)
void seq2seq_kernel(
    const float* __restrict__ inputs,   // [200][4096][4]
    const void* __restrict__ ws,
    const float* __restrict__ Wy,       // [4][100]
    const float* __restrict__ by_g,     // [4]
    float* __restrict__ out)            // [30][4096][4]
{
    __shared__ unsigned short Abuf[2][2048];     // 8 KB
    __shared__ float Wy_lds[404];
    __shared__ unsigned short xstage[200 * 64];  // 25.6 KB

    const unsigned short* fragE = (const unsigned short*)ws;
    const unsigned short* fragD = fragE + FRAG_ELEMS;
    const float* biasE = (const float*)((const char*)ws + BIAS_BYTE_OFF);
    const float* biasD = biasE + 400;

    const int tid = threadIdx.x;
    const int wid = tid >> 6;          // wave 0..15
    const int wl  = tid & 63;
    const int m   = wl & 15;
    const int q   = wl >> 4;
    const int blk = blockIdx.x;

    const int crow = q * 4 + (wl & 3);
    const int ca   = (wl >> 2) & 3;

    for (int i = tid; i < 4096; i += NTHREADS) (&Abuf[0][0])[i] = 0;

    for (int i = tid; i < 200 * 16; i += NTHREADS) {
        int s = i >> 4, u4 = i & 15;
        float4 v = *(const float4*)&inputs[((size_t)s * 4096 + blk * BR + u4) * 4];
        unsigned int pk01, pk23;
        asm("v_cvt_pk_bf16_f32 %0, %1, %2" : "=v"(pk01) : "v"(v.x), "v"(v.y));
        asm("v_cvt_pk_bf16_f32 %0, %1, %2" : "=v"(pk23) : "v"(v.z), "v"(v.w));
        *(unsigned int*)&xstage[i * 4]     = pk01;
        *(unsigned int*)&xstage[i * 4 + 2] = pk23;
    }

    const bool isx = (tid >= 960);
    const int xu = tid - 960;
    const int xr = xu >> 2, xc = xu & 3;
    const int xelem = (192 + xr) * 8 + 4 + xc;

    short8 bfr[2][4]; float breg[2] = {0.f, 0.f};
    #pragma unroll
    for (int i = 0; i < 2; ++i) {
        int t = wid + 16 * i;
        if (t < 25) {
            #pragma unroll
            for (int s = 0; s < 4; ++s)
                bfr[i][s] = *(const short8*)&fragE[((t * 4 + s) * 64 + wl) * 8];
            breg[i] = biasE[t * 16 + m];
        }
    }
    float cst[2] = {0.f, 0.f};
    const short8 zero8 = {0, 0, 0, 0, 0, 0, 0, 0};

    // one encoder step: read Ar, write h into Aw, stage x(step+1) into Aw
    auto enc_body = [&](const unsigned short* Ar, unsigned short* Aw, int step) {
        __syncthreads();                         // Ar complete; Aw free
        if (isx && step < 199)                   // hoisted: hide under compute
            Aw[xelem] = xstage[(step + 1) * 64 + xu];
        short8 af[4];
        #pragma unroll
        for (int s = 0; s < 3; ++s)
            af[s] = *(const short8*)&Ar[(s * 64 + wl) * 8];
        af[3] = zero8;
        if (q == 0)                              // s=3 real only for q==0 lanes
            af[3] = *(const short8*)&Ar[(192 + wl) * 8];
        #pragma unroll
        for (int i = 0; i < 2; ++i) {
            int t = wid + 16 * i;
            if (t < 25) {
                f32x4 acc = {breg[i], breg[i], breg[i], breg[i]};
                #pragma unroll
                for (int s = 0; s < 4; ++s)
                    acc = __builtin_amdgcn_mfma_f32_16x16x32_bf16(af[s], bfr[i][s], acc, 0, 0, 0);
                float h = trans_cell(acc, cst[i], wl);
                int col = 4 * t + ca;
                Aw[((col >> 3) * 16 + crow) * 8 + (col & 7)] = cvt1bf(h);
            }
        }
    };

    __syncthreads();                             // A zeroed + xstage filled
    if (isx) Abuf[0][xelem] = xstage[xu];        // x(0) -> buf 0

    // ---------------- encoder: 200 steps, unrolled x2 ----------------
    for (int step = 0; step < 200; step += 2) {
        enc_body(Abuf[0], Abuf[1], step);
        enc_body(Abuf[1], Abuf[0], step + 1);
    }

    // ---------------- switch to decoder (h_enc in buf[0]) ----------------
    #pragma unroll
    for (int i = 0; i < 2; ++i) {
        int t = wid + 16 * i;
        if (t < 25) {
            #pragma unroll
            for (int s = 0; s < 4; ++s)
                bfr[i][s] = *(const short8*)&fragD[((t * 4 + s) * 64 + wl) * 8];
            breg[i] = biasD[t * 16 + m];
        }
    }
    cst[0] = cst[1] = 0.f;
    if (isx) Abuf[0][xelem] = 0;                 // y_prev = 0
    for (int i = tid; i < 404; i += NTHREADS)
        Wy_lds[i] = (i < 400) ? Wy[i] : by_g[i - 400];

    const int yrow = tid >> 5, yln = tid & 31;
    const bool isy = (tid < 512);

    auto dec_body = [&](const unsigned short* Ar, unsigned short* Aw, int d) {
        __syncthreads();                         // B1: Ar ready (h, y_prev)
        short8 af[4];
        #pragma unroll
        for (int s = 0; s < 3; ++s)
            af[s] = *(const short8*)&Ar[(s * 64 + wl) * 8];
        af[3] = zero8;
        if (q == 0)
            af[3] = *(const short8*)&Ar[(192 + wl) * 8];
        #pragma unroll
        for (int i = 0; i < 2; ++i) {
            int t = wid + 16 * i;
            if (t < 25) {
                f32x4 acc = {breg[i], breg[i], breg[i], breg[i]};
                #pragma unroll
                for (int s = 0; s < 4; ++s)
                    acc = __builtin_amdgcn_mfma_f32_16x16x32_bf16(af[s], bfr[i][s], acc, 0, 0, 0);
                float h = trans_cell(acc, cst[i], wl);
                int col = 4 * t + ca;
                Aw[((col >> 3) * 16 + crow) * 8 + (col & 7)] = cvt1bf(h);
            }
        }
        __syncthreads();                         // B2: h complete in Aw
        if (isy) {
            float p0 = 0.f, p1 = 0.f, p2 = 0.f, p3 = 0.f;
            #pragma unroll
            for (int i = 0; i < 4; ++i) {
                int j = yln + 32 * i;
                if (j < 100) {
                    float hv = bf2f(Aw[((j >> 3) * 16 + yrow) * 8 + (j & 7)]);
                    p0 = fmaf(Wy_lds[0 * 100 + j], hv, p0);
                    p1 = fmaf(Wy_lds[1 * 100 + j], hv, p1);
                    p2 = fmaf(Wy_lds[2 * 100 + j], hv, p2);
                    p3 = fmaf(Wy_lds[3 * 100 + j], hv, p3);
                }
            }
            #pragma unroll
            for (int mm = 16; mm >= 1; mm >>= 1) {
                p0 += __shfl_xor(p0, mm, 32);
                p1 += __shfl_xor(p1, mm, 32);
                p2 += __shfl_xor(p2, mm, 32);
                p3 += __shfl_xor(p3, mm, 32);
            }
            if (yln == 0) {
                float y0 = p0 + Wy_lds[400], y1 = p1 + Wy_lds[401];
                float y2 = p2 + Wy_lds[402], y3 = p3 + Wy_lds[403];
                *(float4*)&out[((size_t)d * 4096 + blk * BR + yrow) * 4] =
                    make_float4(y0, y1, y2, y3);
                unsigned int pk01, pk23;
                asm("v_cvt_pk_bf16_f32 %0, %1, %2" : "=v"(pk01) : "v"(y0), "v"(y1));
                asm("v_cvt_pk_bf16_f32 %0, %1, %2" : "=v"(pk23) : "v"(y2), "v"(y3));
                *(unsigned int*)&Aw[(192 + yrow) * 8 + 4] = pk01;   // y feedback
                *(unsigned int*)&Aw[(192 + yrow) * 8 + 6] = pk23;
            }
        }
    };

    // ---------------- decoder: 30 steps, unrolled x2 ----------------
    for (int d = 0; d < 30; d += 2) {
        dec_body(Abuf[0], Abuf[1], d);
        dec_body(Abuf[1], Abuf[0], d + 1);
    }
}

extern "C" void kernel_launch(void* const* d_in, const int* in_sizes, int n_in,
                              void* d_out, int out_size, void* d_ws, size_t ws_size,
                              hipStream_t stream)
{
    (void)in_sizes; (void)n_in; (void)out_size; (void)ws_size;
    const float* inputs = (const float*)d_in[0];
    const float* Wih_e  = (const float*)d_in[1];
    const float* Whh_e  = (const float*)d_in[2];
    const float* bih_e  = (const float*)d_in[3];
    const float* bhh_e  = (const float*)d_in[4];
    const float* Wih_d  = (const float*)d_in[5];
    const float* Whh_d  = (const float*)d_in[6];
    const float* bih_d  = (const float*)d_in[7];
    const float* bhh_d  = (const float*)d_in[8];
    const float* Wy     = (const float*)d_in[9];
    const float* by     = (const float*)d_in[10];
    float* out = (float*)d_out;

    hipLaunchKernelGGL(prep_kernel, dim3(256), dim3(256), 0, stream,
                       Wih_e, Whh_e, bih_e, bhh_e, Wih_d, Whh_d, bih_d, bhh_d, d_ws);
    hipLaunchKernelGGL(seq2seq_kernel, dim3(NBLOCKS), dim3(NTHREADS), 0, stream,
                       inputs, d_ws, Wy, by, out);
}

// Round 19
// 211.975 us; speedup vs baseline: 1.0193x; 1.0193x over previous
//
#include <hip/hip_runtime.h>

// Seq2seq LSTM, round 19: REVERT to r17 verbatim (best verified: 211.6us
// bench / 230us rocprof). r18's af[3] predication + x-hoist regressed (+4us).
// Structure: 256 blocks x 1024 thr x BR=16, full-M MFMA (16x16x32 bf16,
// weights in VGPRs, prep-built fragments), DPP quad-transpose + in-register
// cell update (no gate LDS round-trip), double-buffered A with ONE barrier
// per encoder step, cvt_pk bf16 stores, LDS x-staging, unrolled x2.
//   i,f,o gates scaled by -log2e -> sigmoid = rcp(1 + exp2(g))
//   g gate scaled by +2*log2e   -> tanh    = 1 - 2*rcp(1 + exp2(g))

#define NTHREADS 1024
#define NBLOCKS  256
#define BR       16

typedef __attribute__((ext_vector_type(8))) short short8;
typedef __attribute__((ext_vector_type(4))) float f32x4;

#define FRAG_ELEMS 51200
#define BIAS_BYTE_OFF 204800
#define L2E 1.4426950408889634f

__device__ __forceinline__ unsigned short f2bf(float f) {
    unsigned int u = __float_as_uint(f);
    return (unsigned short)((u + 0x7fff + ((u >> 16) & 1)) >> 16);   // RNE
}
__device__ __forceinline__ float bf2f(unsigned short s) {
    return __uint_as_float(((unsigned int)s) << 16);
}
__device__ __forceinline__ unsigned short cvt1bf(float f) {     // 1-op HW RNE
    unsigned int pk;
    asm("v_cvt_pk_bf16_f32 %0, %1, %2" : "=v"(pk) : "v"(f), "v"(f));
    return (unsigned short)pk;
}
__device__ __forceinline__ float ex2(float x) {
    float r; asm("v_exp_f32 %0, %1" : "=v"(r) : "v"(x)); return r;
}
__device__ __forceinline__ float rcpf_(float x) { return __builtin_amdgcn_rcpf(x); }

__device__ __forceinline__ float dppx1(float x) {
    return __int_as_float(__builtin_amdgcn_mov_dpp(__float_as_int(x), 0xB1, 0xF, 0xF, true));
}
__device__ __forceinline__ float dppx2(float x) {
    return __int_as_float(__builtin_amdgcn_mov_dpp(__float_as_int(x), 0x4E, 0xF, 0xF, true));
}

// r10/r15-verified 4x4 quad transpose + LSTM cell update. Returns h, updates c.
__device__ __forceinline__ float trans_cell(f32x4 v, float& c, int wl) {
    float s0 = dppx1(v[0]), s1 = dppx1(v[1]), s2 = dppx1(v[2]), s3 = dppx1(v[3]);
    const bool o1 = (wl & 1) != 0;
    float a0 = o1 ? s1 : v[0];
    float a1 = o1 ? v[1] : s0;
    float a2 = o1 ? s3 : v[2];
    float a3 = o1 ? v[3] : s2;
    float u0 = dppx2(a0), u1 = dppx2(a1), u2 = dppx2(a2), u3 = dppx2(a3);
    const bool o2 = (wl & 2) != 0;
    float gi = o2 ? u2 : a0;
    float gf = o2 ? u3 : a1;
    float gg = o2 ? a2 : u0;
    float go = o2 ? a3 : u1;
    float si = rcpf_(1.f + ex2(gi));
    float sf = rcpf_(1.f + ex2(gf));
    float tg = fmaf(-2.f, rcpf_(1.f + ex2(gg)), 1.f);
    float so = rcpf_(1.f + ex2(go));
    c = fmaf(sf, c, si * tg);
    float tc = fmaf(-2.f, rcpf_(1.f + ex2(c * (2.f * L2E))), 1.f);
    return so * tc;
}

// frag[((t*4+s)*64 + lane)*8 + e] = scale(gate) * WT'[k][n], bf16  (r5-identical)
__global__ void prep_kernel(const float* __restrict__ Wih_e, const float* __restrict__ Whh_e,
                            const float* __restrict__ bih_e, const float* __restrict__ bhh_e,
                            const float* __restrict__ Wih_d, const float* __restrict__ Whh_d,
                            const float* __restrict__ bih_d, const float* __restrict__ bhh_d,
                            void* __restrict__ ws)
{
    unsigned short* frag = (unsigned short*)ws;
    float* bias = (float*)((char*)ws + BIAS_BYTE_OFF);
    int gid = blockIdx.x * blockDim.x + threadIdx.x;
    int gsz = gridDim.x * blockDim.x;
    for (int i = gid; i < 2 * FRAG_ELEMS; i += gsz) {
        int which = i / FRAG_ELEMS;
        int e = i - which * FRAG_ELEMS;
        int j8 = e & 7, lane = (e >> 3) & 63, s = (e >> 9) & 3, t = e >> 11;
        int k = s * 32 + (lane >> 4) * 8 + j8;
        int n = t * 16 + (lane & 15);
        int jcol = n >> 2, gate = n & 3, col = gate * 100 + jcol;
        float scale = (gate == 2) ? (2.f * L2E) : -L2E;
        const float* Whh = which ? Whh_d : Whh_e;
        const float* Wih = which ? Wih_d : Wih_e;
        float v = 0.f;
        if (k < 100)      v = Whh[col * 100 + k];
        else if (k < 104) v = Wih[col * 4 + (k - 100)];
        frag[i] = f2bf(v * scale);
    }
    for (int i = gid; i < 800; i += gsz) {
        int which = i / 400, n = i - which * 400;
        int jcol = n >> 2, gate = n & 3, col = gate * 100 + jcol;
        float scale = (gate == 2) ? (2.f * L2E) : -L2E;
        bias[i] = scale * (which ? (bih_d[col] + bhh_d[col]) : (bih_e[col] + bhh_e[col]));
    }
}

__global__ __launch_bounds__(NTHREADS, 4)
void seq2seq_kernel(
    const float* __restrict__ inputs,   // [200][4096][4]
    const void* __restrict__ ws,
    const float* __restrict__ Wy,       // [4][100]
    const float* __restrict__ by_g,     // [4]
    float* __restrict__ out)            // [30][4096][4]
{
    __shared__ unsigned short Abuf[2][2048];     // 8 KB
    __shared__ float Wy_lds[404];
    __shared__ unsigned short xstage[200 * 64];  // 25.6 KB

    const unsigned short* fragE = (const unsigned short*)ws;
    const unsigned short* fragD = fragE + FRAG_ELEMS;
    const float* biasE = (const float*)((const char*)ws + BIAS_BYTE_OFF);
    const float* biasD = biasE + 400;

    const int tid = threadIdx.x;
    const int wid = tid >> 6;          // wave 0..15
    const int wl  = tid & 63;
    const int m   = wl & 15;
    const int q   = wl >> 4;
    const int blk = blockIdx.x;

    const int crow = q * 4 + (wl & 3);
    const int ca   = (wl >> 2) & 3;

    for (int i = tid; i < 4096; i += NTHREADS) (&Abuf[0][0])[i] = 0;

    for (int i = tid; i < 200 * 16; i += NTHREADS) {
        int s = i >> 4, u4 = i & 15;
        float4 v = *(const float4*)&inputs[((size_t)s * 4096 + blk * BR + u4) * 4];
        unsigned int pk01, pk23;
        asm("v_cvt_pk_bf16_f32 %0, %1, %2" : "=v"(pk01) : "v"(v.x), "v"(v.y));
        asm("v_cvt_pk_bf16_f32 %0, %1, %2" : "=v"(pk23) : "v"(v.z), "v"(v.w));
        *(unsigned int*)&xstage[i * 4]     = pk01;
        *(unsigned int*)&xstage[i * 4 + 2] = pk23;
    }

    const bool isx = (tid >= 960);
    const int xu = tid - 960;
    const int xr = xu >> 2, xc = xu & 3;
    const int xelem = (192 + xr) * 8 + 4 + xc;

    short8 bfr[2][4]; float breg[2] = {0.f, 0.f};
    #pragma unroll
    for (int i = 0; i < 2; ++i) {
        int t = wid + 16 * i;
        if (t < 25) {
            #pragma unroll
            for (int s = 0; s < 4; ++s)
                bfr[i][s] = *(const short8*)&fragE[((t * 4 + s) * 64 + wl) * 8];
            breg[i] = biasE[t * 16 + m];
        }
    }
    float cst[2] = {0.f, 0.f};

    // one encoder step: read Ar, write h into Aw, stage x(step+1) into Aw
    auto enc_body = [&](const unsigned short* Ar, unsigned short* Aw, int step) {
        __syncthreads();                         // Ar complete; Aw free
        short8 af[4];
        #pragma unroll
        for (int s = 0; s < 4; ++s)
            af[s] = *(const short8*)&Ar[(s * 64 + wl) * 8];
        #pragma unroll
        for (int i = 0; i < 2; ++i) {
            int t = wid + 16 * i;
            if (t < 25) {
                f32x4 acc = {breg[i], breg[i], breg[i], breg[i]};
                #pragma unroll
                for (int s = 0; s < 4; ++s)
                    acc = __builtin_amdgcn_mfma_f32_16x16x32_bf16(af[s], bfr[i][s], acc, 0, 0, 0);
                float h = trans_cell(acc, cst[i], wl);
                int col = 4 * t + ca;
                Aw[((col >> 3) * 16 + crow) * 8 + (col & 7)] = cvt1bf(h);
            }
        }
        if (isx && step < 199)
            Aw[xelem] = xstage[(step + 1) * 64 + xu];
    };

    __syncthreads();                             // A zeroed + xstage filled
    if (isx) Abuf[0][xelem] = xstage[xu];        // x(0) -> buf 0

    // ---------------- encoder: 200 steps, unrolled x2 ----------------
    for (int step = 0; step < 200; step += 2) {
        enc_body(Abuf[0], Abuf[1], step);
        enc_body(Abuf[1], Abuf[0], step + 1);
    }

    // ---------------- switch to decoder (h_enc in buf[0]) ----------------
    #pragma unroll
    for (int i = 0; i < 2; ++i) {
        int t = wid + 16 * i;
        if (t < 25) {
            #pragma unroll
            for (int s = 0; s < 4; ++s)
                bfr[i][s] = *(const short8*)&fragD[((t * 4 + s) * 64 + wl) * 8];
            breg[i] = biasD[t * 16 + m];
        }
    }
    cst[0] = cst[1] = 0.f;
    if (isx) Abuf[0][xelem] = 0;                 // y_prev = 0
    for (int i = tid; i < 404; i += NTHREADS)
        Wy_lds[i] = (i < 400) ? Wy[i] : by_g[i - 400];

    const int yrow = tid >> 5, yln = tid & 31;
    const bool isy = (tid < 512);

    auto dec_body = [&](const unsigned short* Ar, unsigned short* Aw, int d) {
        __syncthreads();                         // B1: Ar ready (h, y_prev)
        short8 af[4];
        #pragma unroll
        for (int s = 0; s < 4; ++s)
            af[s] = *(const short8*)&Ar[(s * 64 + wl) * 8];
        #pragma unroll
        for (int i = 0; i < 2; ++i) {
            int t = wid + 16 * i;
            if (t < 25) {
                f32x4 acc = {breg[i], breg[i], breg[i], breg[i]};
                #pragma unroll
                for (int s = 0; s < 4; ++s)
                    acc = __builtin_amdgcn_mfma_f32_16x16x32_bf16(af[s], bfr[i][s], acc, 0, 0, 0);
                float h = trans_cell(acc, cst[i], wl);
                int col = 4 * t + ca;
                Aw[((col >> 3) * 16 + crow) * 8 + (col & 7)] = cvt1bf(h);
            }
        }
        __syncthreads();                         // B2: h complete in Aw
        if (isy) {
            float p0 = 0.f, p1 = 0.f, p2 = 0.f, p3 = 0.f;
            #pragma unroll
            for (int i = 0; i < 4; ++i) {
                int j = yln + 32 * i;
                if (j < 100) {
                    float hv = bf2f(Aw[((j >> 3) * 16 + yrow) * 8 + (j & 7)]);
                    p0 = fmaf(Wy_lds[0 * 100 + j], hv, p0);
                    p1 = fmaf(Wy_lds[1 * 100 + j], hv, p1);
                    p2 = fmaf(Wy_lds[2 * 100 + j], hv, p2);
                    p3 = fmaf(Wy_lds[3 * 100 + j], hv, p3);
                }
            }
            #pragma unroll
            for (int mm = 16; mm >= 1; mm >>= 1) {
                p0 += __shfl_xor(p0, mm, 32);
                p1 += __shfl_xor(p1, mm, 32);
                p2 += __shfl_xor(p2, mm, 32);
                p3 += __shfl_xor(p3, mm, 32);
            }
            if (yln == 0) {
                float y0 = p0 + Wy_lds[400], y1 = p1 + Wy_lds[401];
                float y2 = p2 + Wy_lds[402], y3 = p3 + Wy_lds[403];
                *(float4*)&out[((size_t)d * 4096 + blk * BR + yrow) * 4] =
                    make_float4(y0, y1, y2, y3);
                unsigned int pk01, pk23;
                asm("v_cvt_pk_bf16_f32 %0, %1, %2" : "=v"(pk01) : "v"(y0), "v"(y1));
                asm("v_cvt_pk_bf16_f32 %0, %1, %2" : "=v"(pk23) : "v"(y2), "v"(y3));
                *(unsigned int*)&Aw[(192 + yrow) * 8 + 4] = pk01;   // y feedback
                *(unsigned int*)&Aw[(192 + yrow) * 8 + 6] = pk23;
            }
        }
    };

    // ---------------- decoder: 30 steps, unrolled x2 ----------------
    for (int d = 0; d < 30; d += 2) {
        dec_body(Abuf[0], Abuf[1], d);
        dec_body(Abuf[1], Abuf[0], d + 1);
    }
}

extern "C" void kernel_launch(void* const* d_in, const int* in_sizes, int n_in,
                              void* d_out, int out_size, void* d_ws, size_t ws_size,
                              hipStream_t stream)
{
    (void)in_sizes; (void)n_in; (void)out_size; (void)ws_size;
    const float* inputs = (const float*)d_in[0];
    const float* Wih_e  = (const float*)d_in[1];
    const float* Whh_e  = (const float*)d_in[2];
    const float* bih_e  = (const float*)d_in[3];
    const float* bhh_e  = (const float*)d_in[4];
    const float* Wih_d  = (const float*)d_in[5];
    const float* Whh_d  = (const float*)d_in[6];
    const float* bih_d  = (const float*)d_in[7];
    const float* bhh_d  = (const float*)d_in[8];
    const float* Wy     = (const float*)d_in[9];
    const float* by     = (const float*)d_in[10];
    float* out = (float*)d_out;

    hipLaunchKernelGGL(prep_kernel, dim3(256), dim3(256), 0, stream,
                       Wih_e, Whh_e, bih_e, bhh_e, Wih_d, Whh_d, bih_d, bhh_d, d_ws);
    hipLaunchKernelGGL(seq2seq_kernel, dim3(NBLOCKS), dim3(NTHREADS), 0, stream,
                       inputs, d_ws, Wy, by, out);
}